// Round 7
// baseline (246.786 us; speedup 1.0000x reference)
//
#include <hip/hip_runtime.h>

// CostVolume via banded-correlation MFMA (v_mfma_f32_16x16x32_f16), FLIPPED.
// cost[b,h,w,(sh+4)*9+(sw+4)] = LeakyReLU_0.1( mean_c x1[b,h,w,c]*warped[b,h+sh,w+sw,c] )
// B=8 H=128 W=192 C=128, MD=4. Output fp32 [B,H,W,81].
//
// Round-7 vs 59.7us round-4: OPERAND FLIP to halve LDS reads (the largest
// pipe, ~40% busy: 576 ds_read_b128/block + 4.4M conflict cy).
//   OLD: A = x1 (regs), B = warped (LDS, 2 px-windows) -> 18 ds_read/step.
//   NEW: A = warped (regs, both px-windows), B = x1 (LDS) -> the 2 MFMAs of
//        each (r,sh) pair SHARE one B read -> 9 ds_read/step.
// D[m][n] = warped[win px m] . x1[px n]; sw4 = p - n (p = staged warped px,
// tile0 p=m, tile1 p=m+8; tile1 only stores when p>=16 i.e. m>=8).
// Wave wv owns warped local rows rA=wv-4 (sh=-4..wv-4) and rB=wv+4
// (sh=wv-3..4): exactly 9 (r,sh) pairs each; sh4 = q, output row
// l(q) = wv-q (q<=wv) else wv+8-q. Each output element has a unique writer.
// x1 LDS tile is HALO-FREE: [8 rows][16 px] = 8KB/chunk buffer (was 24.6KB
// with 16x24 halo); staging = 1 run/thread, no predicates; LDS 48->16KB.
// Warped halo now loaded straight to per-wave regs (L2-served re-reads).
// Round-6 lesson: no T14 raw parking across MFMA beyond depth-1 (reg blow
// -> 2 waves/SIMD); arch ~75 + 72 AGPR = 147 < 170 keeps 3 waves/SIMD.
// Keeps from round-4: XCD swizzle (192 wg = one image per XCD), direct
// band stores, lgkm-only barriers, double-buffer, depth-2 x1 prefetch.

namespace {
constexpr int Bb = 8, Hh = 128, Ww = 192, Cn = 128;
constexpr int TH = 8, TWT = 16;        // block tile: 8 rows x 16 px
constexpr int NTHR = 512;              // 8 waves
constexpr int KC = 32;                 // channels per chunk
constexpr int NCH = Cn / KC;           // 4
constexpr int ROWB = TWT * 4 * 16;     // 1024 B per x1 LDS row (16px x 4kq x 16B)
constexpr int BUFB = TH * ROWB;        // 8192 B per buffer
constexpr float NEG = 0.1f;
}

typedef __fp16 h2v   __attribute__((ext_vector_type(2)));
typedef __fp16 f16x8 __attribute__((ext_vector_type(8)));
typedef float  f32x4 __attribute__((ext_vector_type(4)));

__device__ __forceinline__ unsigned pkh2(float a, float b) {
    h2v h = __builtin_amdgcn_cvt_pkrtz(a, b);
    return __builtin_bit_cast(unsigned, h);
}

// Barrier with LDS-only drain: global prefetch loads stay in flight across it.
__device__ __forceinline__ void barrier_lgkm() {
    asm volatile("s_waitcnt lgkmcnt(0)\n\ts_barrier" ::: "memory");
}

__global__ __launch_bounds__(NTHR, 3)
void costvol_mfma(const float* __restrict__ x1,
                  const float* __restrict__ wp,
                  float* __restrict__ out)
{
    __shared__ __align__(16) unsigned char smem[2 * BUFB];   // 16 KiB

    const int tid  = threadIdx.x;
    const int wv   = tid >> 6;        // wave 0..7
    const int lane = tid & 63;
    const int nI   = lane & 15;       // A-row m-lane / B-col n = x1 px
    const int kq   = lane >> 4;       // k-group (8 channels)

    // XCD swizzle: 1536 wg = 8 XCDs x 192; 192 = one batch image (12x16).
    const int id = blockIdx.x;
    const int wg = (id & 7) * 192 + (id >> 3);
    const int bx = wg % 12;
    const int t2 = wg / 12;
    const int by = t2 & 15;
    const int bz = t2 >> 4;

    const int w0 = bx * TWT;
    const int h0 = by * TH;
    const int b  = bz;

    // ---- x1 staging: halo-free [8][16] tile, one 8-ch run per thread ----
    const int skq = tid & 3;
    const int sj  = (tid >> 2) & 15;
    const int sl  = tid >> 6;
    const float* xg = x1 + ((size_t)((b * Hh + h0 + sl) * Ww) + w0 + sj) * Cn + skq * 8;
    const int xoff = sl * ROWB + skq * 256 + sj * 16;

    uint4 gp;
    auto LOADX = [&](int ch) {
        float4 u = *reinterpret_cast<const float4*>(xg + ch * KC);
        float4 v = *reinterpret_cast<const float4*>(xg + ch * KC + 4);
        gp = make_uint4(pkh2(u.x, u.y), pkh2(u.z, u.w),
                        pkh2(v.x, v.y), pkh2(v.z, v.w));
    };
    auto WRITEX = [&](int buf) {
        *reinterpret_cast<uint4*>(smem + buf * BUFB + xoff) = gp;
    };

    // ---- warped A-streams: rows rA=wv-4, rB=wv+4; windows px w0-4 / w0+4 ----
    const int hA  = h0 + wv - 4, hB = h0 + wv + 4;
    const int wt0 = w0 - 4 + nI, wt1 = w0 + 4 + nI;
    const bool okA = (unsigned)hA  < (unsigned)Hh;
    const bool okB = (unsigned)hB  < (unsigned)Hh;
    const bool ok0 = (unsigned)wt0 < (unsigned)Ww;
    const bool ok1 = (unsigned)wt1 < (unsigned)Ww;
    const bool pA0 = okA && ok0, pA1 = okA && ok1;
    const bool pB0 = okB && ok0, pB1 = okB && ok1;
    const int rowA = (b * Hh + (okA ? hA : 0)) * Ww;
    const int rowB = (b * Hh + (okB ? hB : 0)) * Ww;
    const int oA0 = (rowA + (ok0 ? wt0 : 0)) * Cn + kq * 8;
    const int oA1 = (rowA + (ok1 ? wt1 : 0)) * Cn + kq * 8;
    const int oB0 = (rowB + (ok0 ? wt0 : 0)) * Cn + kq * 8;
    const int oB1 = (rowB + (ok1 ? wt1 : 0)) * Cn + kq * 8;

    float4 rA0u, rA0v, rA1u, rA1v, rB0u, rB0v, rB1u, rB1v;   // 32 VGPR raw
    auto LOADA = [&](int ch) {
        const float4 z = make_float4(0.f, 0.f, 0.f, 0.f);
        const float* p;
        p = wp + oA0 + ch * KC;
        rA0u = pA0 ? *reinterpret_cast<const float4*>(p)     : z;
        rA0v = pA0 ? *reinterpret_cast<const float4*>(p + 4) : z;
        p = wp + oA1 + ch * KC;
        rA1u = pA1 ? *reinterpret_cast<const float4*>(p)     : z;
        rA1v = pA1 ? *reinterpret_cast<const float4*>(p + 4) : z;
        p = wp + oB0 + ch * KC;
        rB0u = pB0 ? *reinterpret_cast<const float4*>(p)     : z;
        rB0v = pB0 ? *reinterpret_cast<const float4*>(p + 4) : z;
        p = wp + oB1 + ch * KC;
        rB1u = pB1 ? *reinterpret_cast<const float4*>(p)     : z;
        rB1v = pB1 ? *reinterpret_cast<const float4*>(p + 4) : z;
    };
    auto CVT = [&](const float4& u, const float4& v) -> f16x8 {
        uint4 t = make_uint4(pkh2(u.x, u.y), pkh2(u.z, u.w),
                             pkh2(v.x, v.y), pkh2(v.z, v.w));
        return __builtin_bit_cast(f16x8, t);
    };

    f32x4 ac0[9], ac1[9];
#pragma unroll
    for (int q = 0; q < 9; ++q) {
        f32x4 z = {0.f, 0.f, 0.f, 0.f};
        ac0[q] = z; ac1[q] = z;
    }

    // B ds_read base: row l(q) = wv-q (q<=wv) else wv+8-q
    //   addr(q) = sel(baseW, baseW+8*ROWB) - q*ROWB  (q*ROWB is imm per unroll)
    const int baseW  = wv * ROWB + kq * 256 + nI * 16;
    const int baseW8 = baseW + 8 * ROWB;

    // ---- prologue ----
    LOADX(0);
    LOADA(0);
    WRITEX(0);
    LOADX(1);

    int cur = 0;
#pragma unroll
    for (int ch = 0; ch < NCH; ++ch) {
        barrier_lgkm();
        if (ch + 1 < NCH) WRITEX(cur ^ 1);     // x1 chunk ch+1 -> other buffer
        if (ch + 2 < NCH) LOADX(ch + 2);       // prefetch x1 chunk ch+2
        f16x8 aA0 = CVT(rA0u, rA0v), aA1 = CVT(rA1u, rA1v);
        f16x8 aB0 = CVT(rB0u, rB0v), aB1 = CVT(rB1u, rB1v);
        if (ch + 1 < NCH) LOADA(ch + 1);       // rolling warped raw, depth-1
        const unsigned char* base = smem + cur * BUFB;
#pragma unroll
        for (int q = 0; q < 9; ++q) {
            const int sb = (q <= wv) ? baseW : baseW8;
            uint4 bq = *reinterpret_cast<const uint4*>(base + sb - q * ROWB);
            f16x8 bf = __builtin_bit_cast(f16x8, bq);
            f16x8 a0 = (q <= wv) ? aA0 : aB0;
            f16x8 a1 = (q <= wv) ? aA1 : aB1;
            ac0[q] = __builtin_amdgcn_mfma_f32_16x16x32_f16(a0, bf, ac0[q], 0, 0, 0);
            ac1[q] = __builtin_amdgcn_mfma_f32_16x16x32_f16(a1, bf, ac1[q], 0, 0, 0);
        }
        cur ^= 1;
    }

    // ---- direct band stores ----
    // D map: col n = nI = x1 px, row m = kq*4+rg = A-window row.
    // tile0: warped staged px p=m,   sw4 = m - nI,    valid d0 in [0,8]
    // tile1: warped staged px p=m+8, sw4 = m+8 - nI,  valid d1 in [0,8] && m>=8
    //        (p in [8,16) is tile0's territory -> m>=8 dedups)
    // out k = 9*q + sw4 (sh4 == q); row = h0 + l(q). Unique writer per element.
    const float sc = 1.0f / (float)Cn;
#pragma unroll
    for (int q = 0; q < 9; ++q) {
        const int lq = (q <= wv) ? (wv - q) : (wv + 8 - q);
        const size_t rb = ((size_t)((b * Hh + h0 + lq) * Ww) + w0 + nI) * 81 + q * 9;
#pragma unroll
        for (int rg = 0; rg < 4; ++rg) {
            const int m  = kq * 4 + rg;
            const int d0 = m - nI;
            const int d1 = m + 8 - nI;
            if (d0 >= 0 && d0 <= 8) {
                float v = ac0[q][rg] * sc;
                v = (v >= 0.f) ? v : NEG * v;
                out[rb + d0] = v;
            }
            if (m >= 8 && d1 <= 8) {           // d1 >= 1 guaranteed when m>=8
                float v = ac1[q][rg] * sc;
                v = (v >= 0.f) ? v : NEG * v;
                out[rb + d1] = v;
            }
        }
    }
}

extern "C" void kernel_launch(void* const* d_in, const int* in_sizes, int n_in,
                              void* d_out, int out_size, void* d_ws, size_t ws_size,
                              hipStream_t stream) {
    const float* x1 = (const float*)d_in[0];
    const float* wp = (const float*)d_in[1];
    float* out = (float*)d_out;
    dim3 grid(12 * 16 * 8, 1, 1);   // 1536 blocks, XCD-swizzled in-kernel
    costvol_mfma<<<grid, NTHR, 0, stream>>>(x1, wp, out);
}

// Round 8
// 65.235 us; speedup vs baseline: 3.7830x; 3.7830x over previous
//
#include <hip/hip_runtime.h>

// CostVolume via banded-correlation MFMA (v_mfma_f32_16x16x32_f16).
// cost[b,h,w,(sh+4)*9+(sw+4)] = LeakyReLU_0.1( mean_c x1[b,h,w,c]*warped[b,h+sh,w+sw,c] )
// B=8 H=128 W=192 C=128, MD=4. Output fp32 [B,H,W,81].
//
// Round-8 vs 59.7us round-4: SAME 8x16 tile, SAME staging (RH=16 x RPX=24,
// double-buffered, swizzled, lgkm barriers, XCD swizzle, direct band
// stores) -- but 1024 threads: 16 waves, wave-PAIRS split the 9 sh values
// (w&1==0: sh 0..4, w&1==1: sh 5..8). Accumulators 72 -> 40 AGPR/wave;
// combined regs ~<=104 -> 4 waves/SIMD -> the full 16-wave WG is resident:
// 16 waves/CU vs round-4's 12.8 (reg-capped 3/SIMD at 64+72=136).
// This is round-5's wave-split WITHOUT round-5's halo amplification (grid
// stays 1536, staged tile unchanged). Only duplication: x1 row loads x2
// (wave pair shares a row; block-local, L2-hot).
// Round-7 lesson: staging layout / band-store runs / reg budget are
// co-designed -- this keeps all three and changes only WG packing.

namespace {
constexpr int Bb = 8, Hh = 128, Ww = 192, Cn = 128;
constexpr int MDc = 4;
constexpr int TH = 8, TWT = 16;        // block tile: 8 rows x 16 px
constexpr int NTHR = 1024;             // 16 waves = 8 rows x 2 sh-groups
constexpr int RH = 16;                 // staged warped rows  (h0-4 .. h0+11)
constexpr int RPX = 24;                // staged warped px    (w0-4 .. w0+19)
constexpr int KC = 32;                 // channels per chunk
constexpr int NCH = Cn / KC;           // 4
constexpr int KQB = RPX * 16;          // 384 B per kq-plane (24 x 16B slots)
constexpr int ROWB = 4 * KQB;          // 1536 B per staged row
constexpr int BUFB = RH * ROWB;        // 24576 B per buffer
constexpr int RUNS = RH * RPX * 4;     // 1536 8-channel runs per chunk
constexpr int NIT = 2;                 // it1 active only for tid < 512
constexpr float NEG = 0.1f;
}

typedef __fp16 h2v   __attribute__((ext_vector_type(2)));
typedef __fp16 f16x8 __attribute__((ext_vector_type(8)));
typedef float  f32x4 __attribute__((ext_vector_type(4)));

__device__ __forceinline__ unsigned pkh2(float a, float b) {
    h2v h = __builtin_amdgcn_cvt_pkrtz(a, b);
    return __builtin_bit_cast(unsigned, h);
}

// Barrier with LDS-only drain: global prefetch loads stay in flight across it.
__device__ __forceinline__ void barrier_lgkm() {
    asm volatile("s_waitcnt lgkmcnt(0)\n\ts_barrier" ::: "memory");
}

__global__ __launch_bounds__(NTHR, 4)
void costvol_mfma(const float* __restrict__ x1,
                  const float* __restrict__ wp,
                  float* __restrict__ out)
{
    __shared__ __align__(16) unsigned char smem[2 * BUFB];   // 48 KiB

    const int tid  = threadIdx.x;
    const int w    = tid >> 6;        // wave 0..15
    const int wvr  = w >> 1;          // output row within tile: 0..7
    const int shb  = (w & 1) * 5;     // sh group base: 0 or 5
    const int shn  = 5 - (w & 1);     // sh count: 5 (g0) or 4 (g1)
    const int lane = tid & 63;
    const int nI   = lane & 15;       // A-row m / B-col n lane index
    const int kq   = lane >> 4;       // 0..3 : k-group (8 channels each)

    // XCD swizzle: 1536 wg = 8 XCDs x 192; 192 = one batch image (12x16).
    const int id = blockIdx.x;
    const int wg = (id & 7) * 192 + (id >> 3);
    const int bx = wg % 12;
    const int t2 = wg / 12;
    const int by = t2 & 15;
    const int bz = t2 >> 4;

    const int w0 = bx * TWT;
    const int h0 = by * TH;
    const int b  = bz;

    // ---- warped staging decode: run = (row, px, kq), kq innermost ----
    int g_off[NIT]; int l_off[NIT]; bool g_ok[NIT];
#pragma unroll
    for (int it = 0; it < NIT; ++it) {
        int s   = tid + it * NTHR;    // it0: 0..1023, it1: 1024..2047 (valid<1536)
        int skq = s & 3;
        int t   = s >> 2;
        int px  = t % RPX;
        int row = t / RPX;
        int hw  = h0 - MDc + row;
        int ww  = w0 - MDc + px;
        bool ok = (s < RUNS) &&
                  (unsigned)hw < (unsigned)Hh && (unsigned)ww < (unsigned)Ww;
        g_ok[it]  = ok;
        g_off[it] = ((b * Hh + (ok ? hw : 0)) * Ww + (ok ? ww : 0)) * Cn + skq * 8;
        l_off[it] = row * ROWB + skq * KQB + ((px ^ (skq << 1)) * 16);
    }

    uint4 gp[NIT];
    auto LOADCH = [&](int ch) {
#pragma unroll
        for (int it = 0; it < NIT; ++it) {
            if (g_ok[it]) {
                const float* p = wp + g_off[it] + ch * KC;
                float4 u = *reinterpret_cast<const float4*>(p);
                float4 v = *reinterpret_cast<const float4*>(p + 4);
                gp[it] = make_uint4(pkh2(u.x, u.y), pkh2(u.z, u.w),
                                    pkh2(v.x, v.y), pkh2(v.z, v.w));
            } else {
                gp[it] = make_uint4(0u, 0u, 0u, 0u);
            }
        }
    };
    auto WRITEB = [&](int buf) {
        *reinterpret_cast<uint4*>(smem + buf * BUFB + l_off[0]) = gp[0];
        if (tid < RUNS - NTHR)        // it1 run exists only for tid<512
            *reinterpret_cast<uint4*>(smem + buf * BUFB + l_off[1]) = gp[1];
    };

    // issue first staging chunk before x1 loads (staging is the critical path)
    LOADCH(0);

    // ---- x1 rolling raw prefetch: 8 VGPRs hold next chunk's fp32 data ----
    const float* xp = x1 + ((size_t)((b * Hh + h0 + wvr) * Ww) + w0 + nI) * Cn + kq * 8;
    float4 ar_u, ar_v;                 // raw x1 data for the upcoming chunk
    ar_u = *reinterpret_cast<const float4*>(xp);
    ar_v = *reinterpret_cast<const float4*>(xp + 4);

    f32x4 ac0[5], ac1[5];
#pragma unroll
    for (int s = 0; s < 5; ++s) {
        f32x4 z = {0.f, 0.f, 0.f, 0.f};
        ac0[s] = z; ac1[s] = z;
    }

    // per-lane B fragment offset within a staged row; tile1 = ro0 + 128
    const int ro0 = kq * KQB + ((nI ^ (kq << 1)) * 16);

    WRITEB(0); LOADCH(1);

    int cur = 0;
#pragma unroll
    for (int ch = 0; ch < NCH; ++ch) {
        barrier_lgkm();
        if (ch + 1 < NCH) WRITEB(cur ^ 1);
        if (ch + 2 < NCH) LOADCH(ch + 2);
        // convert this chunk's x1 (loaded last step), then issue next chunk
        uint4 afr = make_uint4(pkh2(ar_u.x, ar_u.y), pkh2(ar_u.z, ar_u.w),
                               pkh2(ar_v.x, ar_v.y), pkh2(ar_v.z, ar_v.w));
        if (ch + 1 < NCH) {
            ar_u = *reinterpret_cast<const float4*>(xp + (ch + 1) * KC);
            ar_v = *reinterpret_cast<const float4*>(xp + (ch + 1) * KC + 4);
        }
        f16x8 av = __builtin_bit_cast(f16x8, afr);
        const unsigned char* base = smem + cur * BUFB;
#pragma unroll
        for (int s = 0; s < 5; ++s) {
            if (s < shn) {
                // staged row = wvr + (shb + s); g1 reads rows wvr+5..wvr+8
                const unsigned char* rp = base + (wvr + shb + s) * ROWB;
                uint4 b0 = *reinterpret_cast<const uint4*>(rp + ro0);
                uint4 b1 = *reinterpret_cast<const uint4*>(rp + ro0 + 128);
                ac0[s] = __builtin_amdgcn_mfma_f32_16x16x32_f16(
                    av, __builtin_bit_cast(f16x8, b0), ac0[s], 0, 0, 0);
                ac1[s] = __builtin_amdgcn_mfma_f32_16x16x32_f16(
                    av, __builtin_bit_cast(f16x8, b1), ac1[s], 0, 0, 0);
            }
        }
        cur ^= 1;
    }

    // ---- direct band stores: no LDS round-trip, no barriers ----
    // C/D map: col=n=lane&15, row=m=(lane>>4)*4+reg
    // tile0: staged px p = nI      -> (m, sw4 = nI-m),   valid d=nI-m in [0,8]
    // tile1: staged px p = nI + 8  -> (m, sw4 = nI-m+8), valid d in [-8,0] && nI>=8
    // out k-index = (shb+s)*9 + sw4; sh-groups write disjoint k ranges.
    const float sc = 1.0f / (float)Cn;
    const size_t rowbase = ((size_t)((b * Hh + h0 + wvr) * Ww) + w0) * 81;
#pragma unroll
    for (int rg = 0; rg < 4; ++rg) {
        int m = kq * 4 + rg;
        int d = nI - m;
        bool t0 = (d >= 0 && d <= 8);
        bool t1 = (d >= -8 && d <= 0 && nI >= 8);
        size_t mb = rowbase + (size_t)m * 81 + shb * 9;
#pragma unroll
        for (int s = 0; s < 5; ++s) {
            if (s < shn) {
                if (t0) {
                    float v = ac0[s][rg] * sc;
                    v = (v >= 0.f) ? v : NEG * v;
                    out[mb + s * 9 + d] = v;
                }
                if (t1) {
                    float v = ac1[s][rg] * sc;
                    v = (v >= 0.f) ? v : NEG * v;
                    out[mb + s * 9 + d + 8] = v;
                }
            }
        }
    }
}

extern "C" void kernel_launch(void* const* d_in, const int* in_sizes, int n_in,
                              void* d_out, int out_size, void* d_ws, size_t ws_size,
                              hipStream_t stream) {
    const float* x1 = (const float*)d_in[0];
    const float* wp = (const float*)d_in[1];
    float* out = (float*)d_out;
    dim3 grid(12 * 16 * 8, 1, 1);   // 1536 blocks, XCD-swizzled in-kernel
    costvol_mfma<<<grid, NTHR, 0, stream>>>(x1, wp, out);
}